// Round 5
// baseline (831.836 us; speedup 1.0000x reference)
//
#include <hip/hip_runtime.h>

typedef __attribute__((ext_vector_type(8)))  short short8;   // 8 x bf16 fragment
typedef __attribute__((ext_vector_type(4)))  float f32x4;
typedef __attribute__((ext_vector_type(16))) float f32x16;

constexpr int N_ROWS = 131072;
constexpr int K_CB   = 4096;
constexpr int D_DIM  = 64;
constexpr float EPS_MARGIN = 2.5e-3f;   // in d = |x-c|^2 units

// ---- ws layout (bytes) ----
constexpr size_t CTR_OFF   = 0;                         // int counter
constexpr size_t CSQ_OFF   = 64;                        // 4096 f32 (+|c|^2, for repair)
constexpr size_t NCSQ4_OFF = CSQ_OFF + 16384;           // 4096 x 4 f32 (-0.5|c|^2 replicated)
constexpr size_t CBH_OFF   = NCSQ4_OFF + 65536;         // 4096*64 bf16 hi, pre-swizzled
constexpr size_t CBL_OFF   = CBH_OFF + 524288;          // lo plane
constexpr size_t LIST_OFF  = CBL_OFF + 524288;          // flagged-row list

#define MFMA32(a, b, c) __builtin_amdgcn_mfma_f32_32x32x16_bf16((a), (b), (c), 0, 0, 0)

union Acc16 { f32x16 v; f32x4 q[4]; };

__device__ __forceinline__ unsigned short f2bf(float f) {
    unsigned int u = __builtin_bit_cast(unsigned int, f);
    u = (u + 0x7fffu + ((u >> 16) & 1u)) >> 16;   // RTNE
    return (unsigned short)u;
}
__device__ __forceinline__ float bf2f(unsigned short h) {
    return __builtin_bit_cast(float, ((unsigned int)h) << 16);
}

// swizzled 16B fragment read from a [rows][128B] tile; chunk (2*ks+g) XOR (row&7)
__device__ __forceinline__ short8 ldfrag32(const unsigned char* base, int row, int g, int ks) {
    const int slot = ((2 * ks + g) ^ (row & 7));
    uint4 v = *(const uint4*)(base + row * 128 + slot * 16);
    return __builtin_bit_cast(short8, v);
}

// ---- prep: codebook squared norms (exact fp32) + replicated -0.5*csq ----
__global__ __launch_bounds__(256)
void prep_csq(const float* __restrict__ cb, float* __restrict__ csq,
              float4* __restrict__ ncsq4) {
    const int k = blockIdx.x * 256 + threadIdx.x;
    const float4* row = (const float4*)(cb + (size_t)k * D_DIM);
    float s = 0.f;
    #pragma unroll
    for (int i = 0; i < 16; ++i) {
        float4 v = row[i];
        s = fmaf(v.x, v.x, s); s = fmaf(v.y, v.y, s);
        s = fmaf(v.z, v.z, s); s = fmaf(v.w, v.w, s);
    }
    csq[k] = s;
    const float n = -0.5f * s;
    ncsq4[k] = make_float4(n, n, n, n);
}

// ---- prep: split cb into hi/lo bf16 planes, PRE-SWIZZLED (slot ^= row&7) ----
__global__ __launch_bounds__(256)
void prep_split(const float* __restrict__ cb, unsigned char* __restrict__ cbh,
                unsigned char* __restrict__ cbl) {
    const int id  = blockIdx.x * 256 + threadIdx.x;   // 32768 = 4096 rows * 8 slots
    const int row = id >> 3, s = id & 7;
    const float4* src = (const float4*)(cb + (size_t)row * D_DIM + s * 8);
    float4 v0 = src[0], v1 = src[1];
    float f[8] = {v0.x, v0.y, v0.z, v0.w, v1.x, v1.y, v1.z, v1.w};
    unsigned int hw[4], lw[4];
    #pragma unroll
    for (int i = 0; i < 4; ++i) {
        unsigned short h0 = f2bf(f[2*i]),     l0 = f2bf(f[2*i]     - bf2f(h0));
        unsigned short h1 = f2bf(f[2*i + 1]), l1 = f2bf(f[2*i + 1] - bf2f(h1));
        hw[i] = (unsigned int)h0 | ((unsigned int)h1 << 16);
        lw[i] = (unsigned int)l0 | ((unsigned int)l1 << 16);
    }
    const int slot = s ^ (row & 7);
    *(uint4*)(cbh + (size_t)row * 128 + slot * 16) = make_uint4(hw[0], hw[1], hw[2], hw[3]);
    *(uint4*)(cbl + (size_t)row * 128 + slot * 16) = make_uint4(lw[0], lw[1], lw[2], lw[3]);
}

__global__ void init_counter(int* counter) { if (threadIdx.x == 0) *counter = 0; }

// ---- stage one 64-code tile: hi 8KB | lo 8KB | ncsq4 1KB  via global_load_lds ----
__device__ __forceinline__ void stage_tile(const unsigned char* __restrict__ cbh,
                                           const unsigned char* __restrict__ cbl,
                                           const float* __restrict__ ncsq4,
                                           unsigned char* sm, int kt, int wid, int lane) {
    const unsigned char* sh = cbh + (size_t)kt * 128;
    const unsigned char* sl = cbl + (size_t)kt * 128;
    #pragma unroll
    for (int p = 0; p < 2; ++p) {
        const int chunk = wid * 2 + p;
        __builtin_amdgcn_global_load_lds(
            (const __attribute__((address_space(1))) void*)(sh + chunk * 1024 + lane * 16),
            (__attribute__((address_space(3))) void*)(sm + chunk * 1024), 16, 0, 0);
        __builtin_amdgcn_global_load_lds(
            (const __attribute__((address_space(1))) void*)(sl + chunk * 1024 + lane * 16),
            (__attribute__((address_space(3))) void*)(sm + 8192 + chunk * 1024), 16, 0, 0);
    }
    if (wid == 0) {
        __builtin_amdgcn_global_load_lds(
            (const __attribute__((address_space(1))) void*)
                ((const unsigned char*)ncsq4 + (size_t)kt * 16 + lane * 16),
            (__attribute__((address_space(3))) void*)(sm + 16384), 16, 0, 0);
    }
}

// ---- main: 3-term split-bf16 32x32x16 MFMA, argmax-m, fused gather ----
__global__ __launch_bounds__(256, 4)
void vq_main_mfma(const float* __restrict__ z,
                  const float* __restrict__ cb,
                  const unsigned char* __restrict__ cbh,
                  const unsigned char* __restrict__ cbl,
                  const float* __restrict__ ncsq4,
                  int* __restrict__ list,
                  int* __restrict__ counter, float* __restrict__ out) {
    // per buffer: hi 8K | lo 8K | ncsq4 1K -> 17408 B; two buffers = 34816 B.
    // A-staging (hi 16K @0, lo 16K @16384) transiently spans both buffers.
    __shared__ __align__(16) unsigned char sm[2][17408];
    unsigned char* smf = &sm[0][0];
    const int t = threadIdx.x, lane = t & 63, wid = t >> 6;
    const int g = lane >> 5, colv = lane & 31;
    const int n0 = blockIdx.x * 128;
    const int wbase = wid * 32;

    // stage A tile (128 rows of z) hi/lo swizzled
    #pragma unroll
    for (int p = 0; p < 4; ++p) {
        const int id = t + p * 256;          // 1024 = 128 rows * 8 slots
        const int row = id >> 3, s = id & 7;
        const float4* src = (const float4*)(z + (size_t)(n0 + row) * D_DIM + s * 8);
        float4 v0 = src[0], v1 = src[1];
        float f[8] = {v0.x, v0.y, v0.z, v0.w, v1.x, v1.y, v1.z, v1.w};
        unsigned int hw[4], lw[4];
        #pragma unroll
        for (int i = 0; i < 4; ++i) {
            unsigned short h0 = f2bf(f[2*i]),     l0 = f2bf(f[2*i]     - bf2f(h0));
            unsigned short h1 = f2bf(f[2*i + 1]), l1 = f2bf(f[2*i + 1] - bf2f(h1));
            hw[i] = (unsigned int)h0 | ((unsigned int)h1 << 16);
            lw[i] = (unsigned int)l0 | ((unsigned int)l1 << 16);
        }
        const int slot = s ^ (row & 7);
        *(uint4*)(smf + row * 128 + slot * 16)         = make_uint4(hw[0], hw[1], hw[2], hw[3]);
        *(uint4*)(smf + 16384 + row * 128 + slot * 16) = make_uint4(lw[0], lw[1], lw[2], lw[3]);
    }
    __syncthreads();

    // A fragments: row = wbase + (lane&31), 4 k-steps of 16
    short8 ah[4], al[4];
    {
        const int arow = wbase + colv;
        #pragma unroll
        for (int ks = 0; ks < 4; ++ks) {
            ah[ks] = ldfrag32(smf,         arow, g, ks);
            al[ks] = ldfrag32(smf + 16384, arow, g, ks);
        }
    }
    __syncthreads();   // everyone done reading A before B staging overwrites

    // per-lane state: 16 output rows x (this lane's column per ct)
    float b1[16], b2[16]; int i1[16];
    #pragma unroll
    for (int j = 0; j < 16; ++j) {
        b1[j] = -__builtin_inff(); b2[j] = -__builtin_inff(); i1[j] = 0;
    }

    stage_tile(cbh, cbl, ncsq4, &sm[0][0], 0, wid, lane);
    __syncthreads();   // drains vmcnt(0): tile 0 resident
    int cur = 0;
    for (int kt = 0; kt < K_CB; kt += 64) {
        if (kt + 64 < K_CB)
            stage_tile(cbh, cbl, ncsq4, &sm[cur ^ 1][0], kt + 64, wid, lane);
        const unsigned char* bhp = &sm[cur][0];
        const unsigned char* blp = &sm[cur][8192];
        const unsigned char* ncs_l = &sm[cur][16384];
        #pragma unroll
        for (int ct = 0; ct < 2; ++ct) {
            const int cidx = ct * 32 + colv;            // code row within tile
            short8 bh[4], bl[4];
            #pragma unroll
            for (int ks = 0; ks < 4; ++ks) {
                bh[ks] = ldfrag32(bhp, cidx, g, ks);
                bl[ks] = ldfrag32(blp, cidx, g, ks);
            }
            // acc init = -0.5*|c|^2 broadcast into all 16 regs (LDS pipe, not VALU)
            Acc16 ac;
            const f32x4* ncsp = (const f32x4*)(ncs_l + cidx * 16);
            #pragma unroll
            for (int q = 0; q < 4; ++q) ac.q[q] = *ncsp;
            f32x16 acc = ac.v;
            #pragma unroll
            for (int ks = 0; ks < 4; ++ks) acc = MFMA32(ah[ks], bh[ks], acc);  // xh*ch
            #pragma unroll
            for (int ks = 0; ks < 4; ++ks) acc = MFMA32(al[ks], bh[ks], acc);  // xl*ch
            #pragma unroll
            for (int ks = 0; ks < 4; ++ks) acc = MFMA32(ah[ks], bl[ks], acc);  // xh*cl
            // epilogue: m = dot - 0.5|c|^2 ; running argmax + second-best
            const int idx = kt + cidx;
            #pragma unroll
            for (int j = 0; j < 16; ++j) {
                const float m = acc[j];
                const bool gt = m > b1[j];
                b2[j] = fmaxf(b2[j], gt ? b1[j] : m);
                b1[j] = gt ? m : b1[j];
                i1[j] = gt ? idx : i1[j];
            }
        }
        __syncthreads();   // drains next-tile staging loads; all waves done with cur
        cur ^= 1;
    }

    // cross-lane argmax over the 32 lanes of each half (cols), first-index tie-break
    int* bidx_lds = (int*)&sm[0][0];
    #pragma unroll
    for (int j = 0; j < 16; ++j) {
        float v1 = b1[j], v2 = b2[j]; int j1 = i1[j];
        #pragma unroll
        for (int msk = 1; msk < 32; msk <<= 1) {
            const float ov1 = __shfl_xor(v1, msk);
            const int   oj1 = __shfl_xor(j1, msk);
            const float ov2 = __shfl_xor(v2, msk);
            const bool take = (ov1 > v1) || (ov1 == v1 && oj1 < j1);
            const float nv2 = fmaxf(take ? v1 : v2, take ? ov2 : ov1);
            v1 = take ? ov1 : v1; j1 = take ? oj1 : j1; v2 = nv2;
        }
        if ((lane & 31) == 0) {
            const int rloc = wbase + (j & 3) + 8 * (j >> 2) + 4 * g;
            bidx_lds[rloc] = j1;
            if (2.0f * (v1 - v2) < EPS_MARGIN) {     // d-margin = 2*(m1-m2)
                const int p = atomicAdd(counter, 1);
                list[p] = n0 + rloc;
            }
        }
    }
    __syncthreads();

    // fused gather: write both output slices for this block's 128 rows
    const float4* cb4 = (const float4*)cb;
    float4* out4 = (float4*)out;
    #pragma unroll
    for (int p = 0; p < 8; ++p) {
        const int id  = t + p * 256;       // 2048 = 128 rows * 16 chunks
        const int row = id >> 4, c4 = id & 15;
        const int k = bidx_lds[row];
        const float4 v = cb4[(size_t)k * 16 + c4];
        out4[(size_t)(n0 + row) * 16 + c4] = v;
        out4[(size_t)N_ROWS * 16 + (size_t)(n0 + row) * 16 + c4] = v;
    }
}

// ---- repair: exact fp32 argmin for flagged rows; rewrites their outputs ----
__global__ __launch_bounds__(256)
void repair_kernel(const float* __restrict__ z, const float* __restrict__ cb,
                   const float* __restrict__ csq, const int* __restrict__ list,
                   const int* __restrict__ counter, float* __restrict__ out) {
    __shared__ float xs[64];
    __shared__ float rv[4];
    __shared__ int   ri[4];
    __shared__ int   fi_s;
    const int cnt = counter[0];
    const int t = threadIdx.x;
    for (int e = blockIdx.x; e < cnt; e += gridDim.x) {
        const int row = list[e];
        __syncthreads();
        if (t < 64) xs[t] = z[(size_t)row * D_DIM + t];
        __syncthreads();
        float bv = __builtin_inff(); int bi = 0x7fffffff;
        for (int k = t; k < K_CB; k += 256) {
            const float4* cr = (const float4*)(cb + (size_t)k * D_DIM);
            float dot = 0.f;
            #pragma unroll
            for (int i = 0; i < 16; ++i) {
                float4 v = cr[i];
                dot = fmaf(v.x, xs[i * 4 + 0], dot);
                dot = fmaf(v.y, xs[i * 4 + 1], dot);
                dot = fmaf(v.z, xs[i * 4 + 2], dot);
                dot = fmaf(v.w, xs[i * 4 + 3], dot);
            }
            const float d = fmaf(dot, -2.f, csq[k]);
            if (d < bv) { bv = d; bi = k; }
        }
        #pragma unroll
        for (int msk = 1; msk < 64; msk <<= 1) {
            const float ov = __shfl_xor(bv, msk);
            const int   oi = __shfl_xor(bi, msk);
            if (ov < bv || (ov == bv && oi < bi)) { bv = ov; bi = oi; }
        }
        if ((t & 63) == 0) { rv[t >> 6] = bv; ri[t >> 6] = bi; }
        __syncthreads();
        if (t == 0) {
            float fb = rv[0]; int fi = ri[0];
            #pragma unroll
            for (int w = 1; w < 4; ++w)
                if (rv[w] < fb || (rv[w] == fb && ri[w] < fi)) { fb = rv[w]; fi = ri[w]; }
            fi_s = fi;
        }
        __syncthreads();
        if (t < 32) {
            const int dest = t >> 4, c4 = t & 15;
            const float4 v = ((const float4*)cb)[(size_t)fi_s * 16 + c4];
            float4* dst = (float4*)out + (size_t)dest * N_ROWS * 16 + (size_t)row * 16 + c4;
            *dst = v;
        }
        __syncthreads();
    }
}

extern "C" void kernel_launch(void* const* d_in, const int* in_sizes, int n_in,
                              void* d_out, int out_size, void* d_ws, size_t ws_size,
                              hipStream_t stream) {
    const float* z  = (const float*)d_in[0];
    const float* cb = (const float*)d_in[1];
    float* out = (float*)d_out;
    unsigned char* ws = (unsigned char*)d_ws;

    int*    counter = (int*)(ws + CTR_OFF);
    float*  csq     = (float*)(ws + CSQ_OFF);
    float4* ncsq4   = (float4*)(ws + NCSQ4_OFF);
    unsigned char* cbh = ws + CBH_OFF;
    unsigned char* cbl = ws + CBL_OFF;
    int* list  = (int*)(ws + LIST_OFF);

    prep_csq<<<K_CB / 256, 256, 0, stream>>>(cb, csq, ncsq4);
    prep_split<<<(K_CB * 8) / 256, 256, 0, stream>>>(cb, cbh, cbl);
    init_counter<<<1, 64, 0, stream>>>(counter);
    vq_main_mfma<<<N_ROWS / 128, 256, 0, stream>>>(z, cb, cbh, cbl, (const float*)ncsq4,
                                                   list, counter, out);
    repair_kernel<<<1024, 256, 0, stream>>>(z, cb, csq, list, counter, out);
}

// Round 6
// 355.199 us; speedup vs baseline: 2.3419x; 2.3419x over previous
//
#include <hip/hip_runtime.h>

typedef __attribute__((ext_vector_type(8)))  short short8;   // 8 x bf16 fragment
typedef __attribute__((ext_vector_type(4)))  float f32x4;
typedef __attribute__((ext_vector_type(16))) float f32x16;

constexpr int N_ROWS = 131072;
constexpr int K_CB   = 4096;
constexpr int D_DIM  = 64;
// d-margin flag threshold: split err ~9e-4 + biased-accum ~1.5e-3 + 2x key-trunc ~1.6e-2
constexpr float EPS_FLAG_D = 0.021f;
constexpr float BIAS = 256.0f;          // m+256 in (40,400) by Cauchy-Schwarz -> positive fp32

// ---- ws layout (bytes) ----
constexpr size_t CTR_OFF   = 0;                         // int counter
constexpr size_t CSQ_OFF   = 64;                        // 4096 f32 (+|c|^2, for repair)
constexpr size_t CB4_OFF   = CSQ_OFF + 16384;           // 4096 x 4 f32 (256-0.5|c|^2 replicated)
constexpr size_t CBH_OFF   = CB4_OFF + 65536;           // 4096*64 bf16 hi, pre-swizzled
constexpr size_t CBL_OFF   = CBH_OFF + 524288;          // lo plane
constexpr size_t LIST_OFF  = CBL_OFF + 524288;          // flagged-row list

#define MFMA32(a, b, c) __builtin_amdgcn_mfma_f32_32x32x16_bf16((a), (b), (c), 0, 0, 0)

__device__ __forceinline__ unsigned short f2bf(float f) {
    unsigned int u = __builtin_bit_cast(unsigned int, f);
    u = (u + 0x7fffu + ((u >> 16) & 1u)) >> 16;   // RTNE
    return (unsigned short)u;
}
__device__ __forceinline__ float bf2f(unsigned short h) {
    return __builtin_bit_cast(float, ((unsigned int)h) << 16);
}

// swizzled 16B fragment read from a [rows][128B] tile; chunk (2*ks+g) XOR (row&7)
__device__ __forceinline__ short8 ldfrag32(const unsigned char* base, int row, int g, int ks) {
    const int slot = ((2 * ks + g) ^ (row & 7));
    uint4 v = *(const uint4*)(base + row * 128 + slot * 16);
    return __builtin_bit_cast(short8, v);
}

// pack acc value into sortable key: keep top 25 bits, low 7 = inverted tile code
__device__ __forceinline__ float packkey(float m, unsigned inv) {
    const unsigned u = (__builtin_bit_cast(unsigned, m) & 0xFFFFFF80u) | inv;  // v_and_or_b32
    return __builtin_bit_cast(float, u);
}

// ---- prep: codebook squared norms (exact fp32) + replicated bias-0.5*csq ----
__global__ __launch_bounds__(256)
void prep_csq(const float* __restrict__ cb, float* __restrict__ csq,
              float4* __restrict__ cbias4) {
    const int k = blockIdx.x * 256 + threadIdx.x;
    const float4* row = (const float4*)(cb + (size_t)k * D_DIM);
    float s = 0.f;
    #pragma unroll
    for (int i = 0; i < 16; ++i) {
        float4 v = row[i];
        s = fmaf(v.x, v.x, s); s = fmaf(v.y, v.y, s);
        s = fmaf(v.z, v.z, s); s = fmaf(v.w, v.w, s);
    }
    csq[k] = s;
    const float n = BIAS - 0.5f * s;
    cbias4[k] = make_float4(n, n, n, n);
}

// ---- prep: split cb into hi/lo bf16 planes, PRE-SWIZZLED (slot ^= row&7) ----
__global__ __launch_bounds__(256)
void prep_split(const float* __restrict__ cb, unsigned char* __restrict__ cbh,
                unsigned char* __restrict__ cbl) {
    const int id  = blockIdx.x * 256 + threadIdx.x;   // 32768 = 4096 rows * 8 slots
    const int row = id >> 3, s = id & 7;
    const float4* src = (const float4*)(cb + (size_t)row * D_DIM + s * 8);
    float4 v0 = src[0], v1 = src[1];
    float f[8] = {v0.x, v0.y, v0.z, v0.w, v1.x, v1.y, v1.z, v1.w};
    unsigned int hw[4], lw[4];
    #pragma unroll
    for (int i = 0; i < 4; ++i) {
        unsigned short h0 = f2bf(f[2*i]),     l0 = f2bf(f[2*i]     - bf2f(h0));
        unsigned short h1 = f2bf(f[2*i + 1]), l1 = f2bf(f[2*i + 1] - bf2f(h1));
        hw[i] = (unsigned int)h0 | ((unsigned int)h1 << 16);
        lw[i] = (unsigned int)l0 | ((unsigned int)l1 << 16);
    }
    const int slot = s ^ (row & 7);
    *(uint4*)(cbh + (size_t)row * 128 + slot * 16) = make_uint4(hw[0], hw[1], hw[2], hw[3]);
    *(uint4*)(cbl + (size_t)row * 128 + slot * 16) = make_uint4(lw[0], lw[1], lw[2], lw[3]);
}

__global__ void init_counter(int* counter) { if (threadIdx.x == 0) *counter = 0; }

// ---- stage one 64-code tile: hi 8KB | lo 8KB | cbias4 1KB  via global_load_lds ----
__device__ __forceinline__ void stage_tile(const unsigned char* __restrict__ cbh,
                                           const unsigned char* __restrict__ cbl,
                                           const float* __restrict__ cbias4,
                                           unsigned char* sm, int kt, int wid, int lane) {
    const unsigned char* sh = cbh + (size_t)kt * 128;
    const unsigned char* sl = cbl + (size_t)kt * 128;
    #pragma unroll
    for (int p = 0; p < 2; ++p) {
        const int chunk = wid * 2 + p;
        __builtin_amdgcn_global_load_lds(
            (const __attribute__((address_space(1))) void*)(sh + chunk * 1024 + lane * 16),
            (__attribute__((address_space(3))) void*)(sm + chunk * 1024), 16, 0, 0);
        __builtin_amdgcn_global_load_lds(
            (const __attribute__((address_space(1))) void*)(sl + chunk * 1024 + lane * 16),
            (__attribute__((address_space(3))) void*)(sm + 8192 + chunk * 1024), 16, 0, 0);
    }
    if (wid == 0) {
        __builtin_amdgcn_global_load_lds(
            (const __attribute__((address_space(1))) void*)
                ((const unsigned char*)cbias4 + (size_t)kt * 16 + lane * 16),
            (__attribute__((address_space(3))) void*)(sm + 16384), 16, 0, 0);
    }
}

// ---- main: 3-term split-bf16 32x32x16 MFMA, packed-key argmax, fused gather ----
__global__ __launch_bounds__(256, 3)
void vq_main_mfma(const float* __restrict__ z,
                  const float* __restrict__ cb,
                  const unsigned char* __restrict__ cbh,
                  const unsigned char* __restrict__ cbl,
                  const float* __restrict__ cbias4,
                  int* __restrict__ list,
                  int* __restrict__ counter, float* __restrict__ out) {
    // per buffer: hi 8K | lo 8K | cbias4 1K -> 17408 B; two buffers = 34816 B.
    // A-staging (hi 16K @0, lo 16K @16384) transiently spans both buffers.
    __shared__ __align__(16) unsigned char sm[2][17408];
    unsigned char* smf = &sm[0][0];
    const int t = threadIdx.x, lane = t & 63, wid = t >> 6;
    const int g = lane >> 5, colv = lane & 31;
    const int n0 = blockIdx.x * 128;
    const int wbase = wid * 32;

    // stage A tile (128 rows of z) hi/lo swizzled
    #pragma unroll
    for (int p = 0; p < 4; ++p) {
        const int id = t + p * 256;          // 1024 = 128 rows * 8 slots
        const int row = id >> 3, s = id & 7;
        const float4* src = (const float4*)(z + (size_t)(n0 + row) * D_DIM + s * 8);
        float4 v0 = src[0], v1 = src[1];
        float f[8] = {v0.x, v0.y, v0.z, v0.w, v1.x, v1.y, v1.z, v1.w};
        unsigned int hw[4], lw[4];
        #pragma unroll
        for (int i = 0; i < 4; ++i) {
            unsigned short h0 = f2bf(f[2*i]),     l0 = f2bf(f[2*i]     - bf2f(h0));
            unsigned short h1 = f2bf(f[2*i + 1]), l1 = f2bf(f[2*i + 1] - bf2f(h1));
            hw[i] = (unsigned int)h0 | ((unsigned int)h1 << 16);
            lw[i] = (unsigned int)l0 | ((unsigned int)l1 << 16);
        }
        const int slot = s ^ (row & 7);
        *(uint4*)(smf + row * 128 + slot * 16)         = make_uint4(hw[0], hw[1], hw[2], hw[3]);
        *(uint4*)(smf + 16384 + row * 128 + slot * 16) = make_uint4(lw[0], lw[1], lw[2], lw[3]);
    }
    __syncthreads();

    // A fragments: row = wbase + (lane&31), 4 k-steps of 16
    short8 ah[4], al[4];
    {
        const int arow = wbase + colv;
        #pragma unroll
        for (int ks = 0; ks < 4; ++ks) {
            ah[ks] = ldfrag32(smf,         arow, g, ks);
            al[ks] = ldfrag32(smf + 16384, arow, g, ks);
        }
    }
    __syncthreads();   // everyone done reading A before B staging overwrites

    // per-lane top-2 packed keys (value-bucket | inverted tile-code), no index array
    float k1[16], k2[16];
    #pragma unroll
    for (int j = 0; j < 16; ++j) { k1[j] = 0.0f; k2[j] = 0.0f; }

    stage_tile(cbh, cbl, cbias4, &sm[0][0], 0, wid, lane);
    __syncthreads();   // drains vmcnt(0): tile 0 resident
    int cur = 0;
    for (int kt = 0; kt < K_CB; kt += 64) {
        if (kt + 64 < K_CB)
            stage_tile(cbh, cbl, cbias4, &sm[cur ^ 1][0], kt + 64, wid, lane);
        const unsigned char* bhp = &sm[cur][0];
        const unsigned char* blp = &sm[cur][8192];
        const unsigned char* ncs_l = &sm[cur][16384];
        const unsigned inv0 = 127u - (unsigned)(kt >> 5);   // 127 - 2*ktile
        const unsigned inv1 = inv0 - 1u;

        float keyA[16];
        #pragma unroll
        for (int ct = 0; ct < 2; ++ct) {
            const int cidx = ct * 32 + colv;            // code row within tile
            short8 bh[4], bl[4];
            #pragma unroll
            for (int ks = 0; ks < 4; ++ks) {
                bh[ks] = ldfrag32(bhp, cidx, g, ks);
                bl[ks] = ldfrag32(blp, cidx, g, ks);
            }
            // acc init = BIAS - 0.5*|c|^2 broadcast into all 16 regs
            const f32x4 cbv = *(const f32x4*)(ncs_l + cidx * 16);
            f32x16 acc;
            #pragma unroll
            for (int q = 0; q < 4; ++q)
                #pragma unroll
                for (int w = 0; w < 4; ++w) acc[q * 4 + w] = cbv[w];
            #pragma unroll
            for (int ks = 0; ks < 4; ++ks) acc = MFMA32(ah[ks], bh[ks], acc);  // xh*ch
            #pragma unroll
            for (int ks = 0; ks < 4; ++ks) acc = MFMA32(al[ks], bh[ks], acc);  // xl*ch
            #pragma unroll
            for (int ks = 0; ks < 4; ++ks) acc = MFMA32(ah[ks], bl[ks], acc);  // xh*cl

            if (ct == 0) {
                #pragma unroll
                for (int j = 0; j < 16; ++j) keyA[j] = packkey(acc[j], inv0);
            } else {
                #pragma unroll
                for (int j = 0; j < 16; ++j) {
                    const float kB = packkey(acc[j], inv1);
                    const float kA = keyA[j];
                    // top-2 merge of {k1,k2} with {kA,kB}: med3 = 2nd-largest of 3
                    const float sec = __builtin_amdgcn_fmed3f(k1[j], kA, kB);
                    k1[j] = fmaxf(fmaxf(k1[j], kA), kB);
                    k2[j] = fmaxf(k2[j], sec);
                }
            }
        }
        __syncthreads();   // drains next-tile staging loads; all waves done with cur
        cur ^= 1;
    }

    // cross-lane argmax over the 32 lanes (code columns), packed-key compare
    int* bidx_lds = (int*)&sm[0][0];
    #pragma unroll
    for (int j = 0; j < 16; ++j) {
        float v1 = k1[j], v2 = k2[j]; int cj = colv;
        #pragma unroll
        for (int msk = 1; msk < 32; msk <<= 1) {
            const float ov1 = __shfl_xor(v1, msk);
            const float ov2 = __shfl_xor(v2, msk);
            const int   oc  = __shfl_xor(cj, msk);
            const bool take = (ov1 > v1) || (ov1 == v1 && oc < cj);
            const float nv2 = fmaxf(take ? v1 : v2, take ? ov2 : ov1);
            v1 = take ? ov1 : v1; cj = take ? oc : cj; v2 = nv2;
        }
        if ((lane & 31) == 0) {
            const unsigned u1 = __builtin_bit_cast(unsigned, v1);
            const int tc = 127 - (int)(u1 & 127u);
            const int idx = tc * 32 + cj;               // ktile*64 + ct*32 + col
            const int rloc = wbase + (j & 3) + 8 * (j >> 2) + 4 * g;
            bidx_lds[rloc] = idx;
            // bucketed margin in d-units = 2*(m1-m2); biases cancel
            const float f1 = __builtin_bit_cast(float, u1 & 0xFFFFFF80u);
            const float f2 = __builtin_bit_cast(float,
                                __builtin_bit_cast(unsigned, v2) & 0xFFFFFF80u);
            if (2.0f * (f1 - f2) < EPS_FLAG_D) {
                const int p = atomicAdd(counter, 1);
                list[p] = n0 + rloc;
            }
        }
    }
    __syncthreads();

    // fused gather: write both output slices for this block's 128 rows
    const float4* cb4 = (const float4*)cb;
    float4* out4 = (float4*)out;
    #pragma unroll
    for (int p = 0; p < 8; ++p) {
        const int id  = t + p * 256;       // 2048 = 128 rows * 16 chunks
        const int row = id >> 4, c4 = id & 15;
        const int k = bidx_lds[row];
        const float4 v = cb4[(size_t)k * 16 + c4];
        out4[(size_t)(n0 + row) * 16 + c4] = v;
        out4[(size_t)N_ROWS * 16 + (size_t)(n0 + row) * 16 + c4] = v;
    }
}

// ---- repair: exact fp32 argmin for flagged rows; rewrites their outputs ----
__global__ __launch_bounds__(256)
void repair_kernel(const float* __restrict__ z, const float* __restrict__ cb,
                   const float* __restrict__ csq, const int* __restrict__ list,
                   const int* __restrict__ counter, float* __restrict__ out) {
    __shared__ float xs[64];
    __shared__ float rv[4];
    __shared__ int   ri[4];
    __shared__ int   fi_s;
    const int cnt = counter[0];
    const int t = threadIdx.x;
    for (int e = blockIdx.x; e < cnt; e += gridDim.x) {
        const int row = list[e];
        __syncthreads();
        if (t < 64) xs[t] = z[(size_t)row * D_DIM + t];
        __syncthreads();
        float bv = __builtin_inff(); int bi = 0x7fffffff;
        for (int k = t; k < K_CB; k += 256) {
            const float4* cr = (const float4*)(cb + (size_t)k * D_DIM);
            float dot = 0.f;
            #pragma unroll
            for (int i = 0; i < 16; ++i) {
                float4 v = cr[i];
                dot = fmaf(v.x, xs[i * 4 + 0], dot);
                dot = fmaf(v.y, xs[i * 4 + 1], dot);
                dot = fmaf(v.z, xs[i * 4 + 2], dot);
                dot = fmaf(v.w, xs[i * 4 + 3], dot);
            }
            const float d = fmaf(dot, -2.f, csq[k]);
            if (d < bv) { bv = d; bi = k; }
        }
        #pragma unroll
        for (int msk = 1; msk < 64; msk <<= 1) {
            const float ov = __shfl_xor(bv, msk);
            const int   oi = __shfl_xor(bi, msk);
            if (ov < bv || (ov == bv && oi < bi)) { bv = ov; bi = oi; }
        }
        if ((t & 63) == 0) { rv[t >> 6] = bv; ri[t >> 6] = bi; }
        __syncthreads();
        if (t == 0) {
            float fb = rv[0]; int fi = ri[0];
            #pragma unroll
            for (int w = 1; w < 4; ++w)
                if (rv[w] < fb || (rv[w] == fb && ri[w] < fi)) { fb = rv[w]; fi = ri[w]; }
            fi_s = fi;
        }
        __syncthreads();
        if (t < 32) {
            const int dest = t >> 4, c4 = t & 15;
            const float4 v = ((const float4*)cb)[(size_t)fi_s * 16 + c4];
            float4* dst = (float4*)out + (size_t)dest * N_ROWS * 16 + (size_t)row * 16 + c4;
            *dst = v;
        }
        __syncthreads();
    }
}

extern "C" void kernel_launch(void* const* d_in, const int* in_sizes, int n_in,
                              void* d_out, int out_size, void* d_ws, size_t ws_size,
                              hipStream_t stream) {
    const float* z  = (const float*)d_in[0];
    const float* cb = (const float*)d_in[1];
    float* out = (float*)d_out;
    unsigned char* ws = (unsigned char*)d_ws;

    int*    counter = (int*)(ws + CTR_OFF);
    float*  csq     = (float*)(ws + CSQ_OFF);
    float4* cbias4  = (float4*)(ws + CB4_OFF);
    unsigned char* cbh = ws + CBH_OFF;
    unsigned char* cbl = ws + CBL_OFF;
    int* list  = (int*)(ws + LIST_OFF);

    prep_csq<<<K_CB / 256, 256, 0, stream>>>(cb, csq, cbias4);
    prep_split<<<(K_CB * 8) / 256, 256, 0, stream>>>(cb, cbh, cbl);
    init_counter<<<1, 64, 0, stream>>>(counter);
    vq_main_mfma<<<N_ROWS / 128, 256, 0, stream>>>(z, cb, cbh, cbl, (const float*)cbias4,
                                                   list, counter, out);
    repair_kernel<<<4096, 256, 0, stream>>>(z, cb, csq, list, counter, out);
}